// Round 4
// baseline (254.231 us; speedup 1.0000x reference)
//
#include <hip/hip_runtime.h>

// PennSkipGramModel forward: mean over B of
//   -logsig(clip(u_l·v_l)) + -logsig(clip(u_r·v_r))
//   + sum_k -logsig(-clip(u_l·neg_l[k])) + sum_k -logsig(-clip(u_r·neg_r[k]))
//
// R3 lesson: three memory structures (serial 16-lane, prefetch 16-lane,
// wave-per-element) all land at 85-90us; FETCH is already the compulsory
// 226MB. VALUBusy 43% and 72 shuffle+adds/element say the REDUCTION is the
// untested co-limiter.
//
// This version: reduce-scatter butterfly. All 12 dot-sums reduced
// SIMULTANEOUSLY: 16 component slots/lane, recursive halving on masks
// 32/16/8/4 (split component set + sum), then 2/1 (pure sum). 17 shuffles
// instead of 72. Component c's full sum lands in lanes (lane>>2)&15==c;
// each lane applies clip/logsig to its own component, one final red64
// combines the 12 terms. Cross-lane ops/element: 72 -> 23.
// Memory side identical to R3 (14 x dwordx2, full prefetch) — clean A/B.

#define BATCH 65536
#define K     5

__device__ __forceinline__ float clip10(float x) {
    return fminf(fmaxf(x, -10.0f), 10.0f);
}

__device__ __forceinline__ float dot2(float2 a, float2 b) {
    return a.x * b.x + a.y * b.y;
}

__global__ __launch_bounds__(1024) void skipgram_fwd(
    const float* __restrict__ u_l, const float* __restrict__ u_r,
    const float* __restrict__ v_l, const float* __restrict__ v_r,
    const int* __restrict__ pos_u, const int* __restrict__ pos_vl,
    const int* __restrict__ pos_vr, const int* __restrict__ neg_vl,
    const int* __restrict__ neg_vr, float* __restrict__ out)
{
    const int tid  = threadIdx.x;
    const int lane = tid & 63;
    const int wid  = __builtin_amdgcn_readfirstlane(tid >> 6);   // 0..15
    const int b    = (blockIdx.x << 4) + wid;

    // ---- phase 0: 13 wave-uniform index loads (scalar) ----
    const int iu  = pos_u[b];
    const int ivl = pos_vl[b];
    const int ivr = pos_vr[b];
    int inl[K], inr[K];
    #pragma unroll
    for (int k = 0; k < K; ++k) {
        inl[k] = neg_vl[b * K + k];
        inr[k] = neg_vr[b * K + k];
    }

    // ---- phase 1: all 14 row loads (float2/lane = 512B/row/instr) ----
    const float2* ULr = (const float2*)u_l + ((size_t)iu  << 6);
    const float2* URr = (const float2*)u_r + ((size_t)iu  << 6);
    const float2* VLr = (const float2*)v_l + ((size_t)ivl << 6);
    const float2* VRr = (const float2*)v_r + ((size_t)ivr << 6);

    float2 ul = ULr[lane];
    float2 ur = URr[lane];
    float2 vl = VLr[lane];
    float2 vr = VRr[lane];

    float2 nl[K], nr[K];
    #pragma unroll
    for (int k = 0; k < K; ++k) {
        nl[k] = ((const float2*)v_l + ((size_t)inl[k] << 6))[lane];
        nr[k] = ((const float2*)v_r + ((size_t)inr[k] << 6))[lane];
    }

    __builtin_amdgcn_sched_barrier(0);

    // ---- phase 2: per-lane partial dots into 16 component slots ----
    // c0=sl c1=sr c2..6=snl[k] c7..11=snr[k] c12..15=pad
    float v[16];
    v[0] = dot2(ul, vl);
    v[1] = dot2(ur, vr);
    #pragma unroll
    for (int k = 0; k < K; ++k) {
        v[2 + k] = dot2(ul, nl[k]);
        v[7 + k] = dot2(ur, nr[k]);
    }
    #pragma unroll
    for (int i = 12; i < 16; ++i) v[i] = 0.0f;

    // ---- phase 3: reduce-scatter butterfly (17 shuffles total) ----
    // masks 32/16/8/4: halve the component set, summing the kept half
    #pragma unroll
    for (int s = 8; s >= 1; s >>= 1) {
        const int  m  = s << 2;                 // 32,16,8,4
        const bool hi = (lane & m) != 0;
        #pragma unroll
        for (int i = 0; i < s; ++i) {
            float send = hi ? v[i] : v[i + s];   // what the partner needs
            float keep = hi ? v[i + s] : v[i];   // what we keep
            v[i] = keep + __shfl_xor(send, m);
        }
    }
    // masks 2/1: finish the 64-lane sum of the single remaining component
    float S = v[0];
    S += __shfl_xor(S, 2);
    S += __shfl_xor(S, 1);

    // lane's component index; full sum of component c is in all 4 lanes
    // with (lane>>2)&15 == c
    const int c = (lane >> 2) & 15;
    const float sc = clip10(S);
    // c<2: -logsig(s) = log(1+exp(-s));  c in 2..11: -logsig(-s) = log(1+exp(s))
    const float x = (c < 2) ? -sc : sc;
    float term = __logf(1.0f + __expf(x));
    term = (c < 12) ? term : 0.0f;

    // 64-lane sum = 4 x (element total): each component replicated in 4 lanes
    term += __shfl_xor(term, 32);
    term += __shfl_xor(term, 16);
    term += __shfl_xor(term, 8);
    term += __shfl_xor(term, 4);
    term += __shfl_xor(term, 2);
    term += __shfl_xor(term, 1);
    const float acc = term * 0.25f;

    // ---- block reduction: 16 waves -> 1 atomic per block ----
    __shared__ float smem[16];
    if (lane == 0) smem[wid] = acc;
    __syncthreads();
    if (tid == 0) {
        float s = 0.0f;
        #pragma unroll
        for (int i = 0; i < 16; ++i) s += smem[i];
        atomicAdd(out, s * (1.0f / BATCH));
    }
}

extern "C" void kernel_launch(void* const* d_in, const int* in_sizes, int n_in,
                              void* d_out, int out_size, void* d_ws, size_t ws_size,
                              hipStream_t stream) {
    const float* u_l   = (const float*)d_in[0];
    const float* u_r   = (const float*)d_in[1];
    const float* v_l   = (const float*)d_in[2];
    const float* v_r   = (const float*)d_in[3];
    const int* pos_u   = (const int*)d_in[4];
    const int* pos_vl  = (const int*)d_in[5];
    const int* pos_vr  = (const int*)d_in[6];
    const int* neg_vl  = (const int*)d_in[7];
    const int* neg_vr  = (const int*)d_in[8];
    float* out = (float*)d_out;

    // d_out is poisoned (0xAA) before every timed launch — zero it on-stream.
    hipMemsetAsync(out, 0, sizeof(float), stream);

    skipgram_fwd<<<BATCH / 16, 1024, 0, stream>>>(
        u_l, u_r, v_l, v_r, pos_u, pos_vl, pos_vr, neg_vl, neg_vr, out);
}